// Round 9
// baseline (2325.326 us; speedup 1.0000x reference)
//
#include <hip/hip_runtime.h>
#include <hip/hip_bf16.h>
#include <math.h>

typedef __bf16 bf16x8 __attribute__((ext_vector_type(8)));
typedef float floatx4 __attribute__((ext_vector_type(4)));

#define T_LEN 128

// ws layout: bf16 fragment-packed weights (unchanged from R5-R8)
#define WP_OFF   0
#define WP_SZ    (64*10*64*16)     // gates: 64 ct x 10 ki x 64 lanes x 16B = 655360
#define W1P_OFF  (WP_OFF + WP_SZ)
#define W1P_SZ   (8*8*64*16)       // 65536
#define W2P_OFF  (W1P_OFF + W1P_SZ)
#define W2P_SZ   (8*4*64*16)       // 32768
#define WZP_OFF  (W2P_OFF + W2P_SZ)
#define WZP_SZ   (4*4*64*16)       // 16384
#define WS_NEEDED ((size_t)(WZP_OFF + WZP_SZ))   // 770048 B

// s_waitcnt imm: wait until <=N vmem outstanding
#define WAITVM(N) (((N) & 0xF) | (0x7 << 4) | (0xF << 8) | (((N) >> 4) << 14))

__device__ __forceinline__ void dma16(const void* g, void* lds) {
    __builtin_amdgcn_global_load_lds(
        (const __attribute__((address_space(1))) void*)g,
        (__attribute__((address_space(3))) void*)lds,
        16, 0, 0);
}

// ---------------- prep: f32 weights -> bf16 B-fragment-linear in ws -------
__global__ void prep_kernel(const float* __restrict__ Wih, const float* __restrict__ Whh,
                            const float* __restrict__ W1,  const float* __restrict__ W2,
                            const float* __restrict__ Wz,  unsigned char* __restrict__ ws)
{
    int id = blockIdx.x * blockDim.x + threadIdx.x;
    __bf16* Wp  = (__bf16*)(ws + WP_OFF);
    __bf16* W1p = (__bf16*)(ws + W1P_OFF);
    __bf16* W2p = (__bf16*)(ws + W2P_OFF);
    __bf16* Wzp = (__bf16*)(ws + WZP_OFF);
    if (id < 40960) {                       // gates: 64 ct x 10 ki x 64 lanes
        int rem = id % 640, lane = rem % 64;
        int row = (id / 640) * 16 + (lane & 15);
        int kb  = (rem / 64) * 32 + (lane >> 4) * 8;
        for (int j = 0; j < 8; ++j) {
            int k = kb + j;
            float v;
            if (k < 40)       v = Wih[row * 40 + k];
            else if (k < 296) v = Whh[row * 256 + (k - 40)];
            else              v = 0.0f;                   // K-pad 296..319
            Wp[(size_t)id * 8 + j] = (__bf16)v;
        }
    } else if (id < 45056) {                // W1: 8 ct x 8 ki
        int id2 = id - 40960;
        int rem = id2 % 512, lane = rem % 64;
        int row = (id2 / 512) * 16 + (lane & 15);
        int kb  = (rem / 64) * 32 + (lane >> 4) * 8;
        for (int j = 0; j < 8; ++j) W1p[(size_t)id2 * 8 + j] = (__bf16)W1[row * 256 + kb + j];
    } else if (id < 47104) {                // W2: 8 ct x 4 ki
        int id3 = id - 45056;
        int rem = id3 % 256, lane = rem % 64;
        int row = (id3 / 256) * 16 + (lane & 15);
        int kb  = (rem / 64) * 32 + (lane >> 4) * 8;
        for (int j = 0; j < 8; ++j) W2p[(size_t)id3 * 8 + j] = (__bf16)W2[row * 128 + kb + j];
    } else if (id < 48128) {                // Wz: 4 ct x 4 ki
        int id4 = id - 47104;
        int rem = id4 % 256, lane = rem % 64;
        int row = (id4 / 256) * 16 + (lane & 15);
        int kb  = (rem / 64) * 32 + (lane >> 4) * 8;
        for (int j = 0; j < 8; ++j) Wzp[(size_t)id4 * 8 + j] = (__bf16)Wz[row * 128 + kb + j];
    }
}

// ---------------- fast path: 64 blocks x 1024 threads, 16 rows/block ------
// 4 barriers/step (ping-pong state buffer + fused zz/z), cross-step DMA
// prefetch so gates slabs are LDS-resident when the K-loop starts.
__global__ __launch_bounds__(1024) void seq_mfma(
    const float* __restrict__ A,   const float* __restrict__ eps,
    const float* __restrict__ z0,  const float* __restrict__ h0,
    const float* __restrict__ c0,
    const float* __restrict__ bih, const float* __restrict__ bhh,
    const float* __restrict__ b1,  const float* __restrict__ b2,
    const float* __restrict__ bz,
    const unsigned char* __restrict__ ws, float* __restrict__ out)
{
    const int tid  = threadIdx.x;
    const int wave = tid >> 6;
    const int lane = tid & 63;
    const int lrow = lane & 15;
    const int quad = lane >> 4;
    const int n0   = blockIdx.x * 16;

    __shared__ __align__(16) __bf16 slots[16][2][2048];  // per-wave 2 x 4KB slabs
    __shared__ __align__(16) __bf16 xh[2][16][328];      // ping-pong [a|z|h|pad]
    __shared__ __align__(16) __bf16 u1s[16][136];
    __shared__ __align__(16) __bf16 u2s[16][136];

    // per-lane global fragment pointers
    const char* gbase[4];
    #pragma unroll
    for (int g = 0; g < 4; ++g)
        gbase[g] = (const char*)ws + WP_OFF + ((size_t)((g * 16 + wave) * 10) * 64 + lane) * 16;
    const char* u1base = (const char*)ws + W1P_OFF + ((size_t)((wave & 7) * 8) * 64 + lane) * 16;
    const char* u2base = (const char*)ws + W2P_OFF + ((size_t)((wave & 7) * 4) * 64 + lane) * 16;
    const char* uz0    = (const char*)ws + WZP_OFF + ((size_t)((wave & 1) * 4) * 64 + lane) * 16;
    const char* uz2    = uz0 + 2 * 4 * 1024;             // ct = wave+2 (raw cols)

    const int unit = wave * 16 + lrow;
    float gb[4];
    #pragma unroll
    for (int g = 0; g < 4; ++g)
        gb[g] = bih[g * 256 + unit] + bhh[g * 256 + unit];
    float u1b = b1[(wave & 7) * 16 + lrow];
    float u2b = b2[(wave & 7) * 16 + lrow];
    float zbL = bz[(wave & 1) * 16 + lrow];              // loc bias (ct = wave)
    float zbR = bz[((wave & 1) + 2) * 16 + lrow];        // raw bias (ct = wave+2)

    float cst[4];
    {
        float cv = c0[unit];
        #pragma unroll
        for (int r = 0; r < 4; ++r) cst[r] = cv;
    }

    // init buf0 z/h + pads of BOTH buffers (pads never rewritten)
    for (int idx = tid; idx < 16 * 320; idx += 1024) {
        int r = idx / 320, col = 8 + idx % 320;
        float v;
        if (col < 40)       v = z0[col - 8];
        else if (col < 296) v = h0[col - 40];
        else                v = 0.0f;
        xh[0][r][col] = (__bf16)v;
        if (col >= 296) xh[1][r][col] = (__bf16)0.0f;
    }

    // prefetch a(t=0) (waves 2,3) and kick initial slabs (all waves)
    float a_cur = 0.0f;
    if (tid >= 128 && tid < 256)
        a_cur = A[((size_t)(n0 + ((tid - 128) >> 3)) * T_LEN + 0) * 8 + ((tid - 128) & 7)];
    #pragma unroll
    for (int g = 0; g < 4; ++g) dma16(gbase[g],        &slots[wave][0][g * 512]);
    #pragma unroll
    for (int g = 0; g < 4; ++g) dma16(gbase[g] + 1024, &slots[wave][1][g * 512]);

    for (int t = 0; t < T_LEN; ++t) {
        const int tb = t & 1, nb = tb ^ 1;

        // ---- stage a_t (waves 2,3) into current buffer
        if (tid >= 128 && tid < 256)
            xh[tb][(tid - 128) >> 3][(tid - 128) & 7] = (__bf16)a_cur;
        __syncthreads();   // B1: drains prefetched slabs; a,z,h visible

        // ---- early prefetches (oldest in queue; drained by first waits/barriers)
        float epsr[4];
        if (wave < 2) {
            #pragma unroll
            for (int r = 0; r < 4; ++r)
                epsr[r] = eps[((size_t)(n0 + quad * 4 + r) * T_LEN + t) * 32 + (wave & 1) * 16 + lrow];
        }
        float a_nxt = 0.0f;
        if (t + 1 < T_LEN && tid >= 128 && tid < 256)
            a_nxt = A[((size_t)(n0 + ((tid - 128) >> 3)) * T_LEN + (t + 1)) * 8 + ((tid - 128) & 7)];

        // ---- gates: slabs 0,1 already resident; wait only for refills (ki>=2)
        floatx4 acc[4];
        #pragma unroll
        for (int g = 0; g < 4; ++g)
            acc[g] = (floatx4){gb[g], gb[g], gb[g], gb[g]};

        bf16x8 afr = *(const bf16x8*)&xh[tb][lrow][quad * 8];
        #pragma unroll
        for (int ki = 0; ki < 10; ++ki) {
            const int s = ki & 1;
            bf16x8 anx = (ki < 9) ? *(const bf16x8*)&xh[tb][lrow][(ki + 1) * 32 + quad * 8] : afr;
            if (ki >= 2) __builtin_amdgcn_s_waitcnt(WAITVM(4));
            #pragma unroll
            for (int g = 0; g < 4; ++g) {
                bf16x8 b = *(const bf16x8*)&slots[wave][s][g * 512 + lane * 8];
                acc[g] = __builtin_amdgcn_mfma_f32_16x16x32_bf16(afr, b, acc[g], 0, 0, 0);
            }
            __builtin_amdgcn_sched_barrier(0);   // slot reads before overwrite
            if (ki + 2 < 10) {
                #pragma unroll
                for (int g = 0; g < 4; ++g)
                    dma16(gbase[g] + (ki + 2) * 1024, &slots[wave][s][g * 512]);
            } else if (ki == 8) {
                if (wave < 8) {
                    #pragma unroll
                    for (int f = 0; f < 4; ++f)
                        dma16(u1base + f * 1024, &slots[wave][0][f * 512]);
                }
            } else {                             // ki == 9
                if (wave < 8) {
                    #pragma unroll
                    for (int f = 0; f < 4; ++f)
                        dma16(u1base + (4 + f) * 1024, &slots[wave][1][f * 512]);
                } else {                         // waves 8-15: next-step slabs now
                    #pragma unroll
                    for (int g = 0; g < 4; ++g) dma16(gbase[g],        &slots[wave][0][g * 512]);
                    #pragma unroll
                    for (int g = 0; g < 4; ++g) dma16(gbase[g] + 1024, &slots[wave][1][g * 512]);
                }
            }
            afr = anx;
        }
        // no barrier: cell writes target buffer nb (disjoint from gates reads)

        // ---- LSTM cell -> h into NEXT buffer
        #pragma unroll
        for (int r = 0; r < 4; ++r) {
            float iv = 1.0f / (1.0f + expf(-acc[0][r]));
            float fv = 1.0f / (1.0f + expf(-acc[1][r]));
            float gv = tanhf(acc[2][r]);
            float ov = 1.0f / (1.0f + expf(-acc[3][r]));
            float cn = fv * cst[r] + iv * gv;
            cst[r] = cn;
            xh[nb][quad * 4 + r][40 + unit] = (__bf16)(ov * tanhf(cn));
        }
        __syncthreads();   // B2: h visible; drains u1 slabs + wave8-15 kicks

        // ---- u1 = relu(h @ W1^T + b1): waves 0..7
        if (wave < 8) {
            floatx4 a1 = (floatx4){u1b, u1b, u1b, u1b};
            #pragma unroll
            for (int ki = 0; ki < 8; ++ki) {
                bf16x8 a = *(const bf16x8*)&xh[nb][lrow][40 + ki * 32 + quad * 8];
                bf16x8 b = *(const bf16x8*)&slots[wave][ki >> 2][(ki & 3) * 512 + lane * 8];
                a1 = __builtin_amdgcn_mfma_f32_16x16x32_bf16(a, b, a1, 0, 0, 0);
            }
            #pragma unroll
            for (int r = 0; r < 4; ++r)
                u1s[quad * 4 + r][wave * 16 + lrow] = (__bf16)fmaxf(a1[r], 0.0f);
            __builtin_amdgcn_sched_barrier(0);
            #pragma unroll
            for (int f = 0; f < 4; ++f)                 // u2 weights -> slot0
                dma16(u2base + f * 1024, &slots[wave][0][f * 512]);
            if (wave >= 2) {                            // waves 2-7: next s1 early
                #pragma unroll
                for (int g = 0; g < 4; ++g)
                    dma16(gbase[g] + 1024, &slots[wave][1][g * 512]);
            }
        }
        __syncthreads();   // B3: u1s ready; u2/next-s1 slabs drained

        // ---- u2 = relu(u1 @ W2^T + b2): waves 0..7
        if (wave < 8) {
            floatx4 a2 = (floatx4){u2b, u2b, u2b, u2b};
            #pragma unroll
            for (int ki = 0; ki < 4; ++ki) {
                bf16x8 a = *(const bf16x8*)&u1s[lrow][ki * 32 + quad * 8];
                bf16x8 b = *(const bf16x8*)&slots[wave][0][ki * 512 + lane * 8];
                a2 = __builtin_amdgcn_mfma_f32_16x16x32_bf16(a, b, a2, 0, 0, 0);
            }
            #pragma unroll
            for (int r = 0; r < 4; ++r)
                u2s[quad * 4 + r][wave * 16 + lrow] = (__bf16)fmaxf(a2[r], 0.0f);
            __builtin_amdgcn_sched_barrier(0);
            if (wave < 2) {                             // wz: ct=w -> slot0, ct=w+2 -> slot1
                #pragma unroll
                for (int f = 0; f < 4; ++f) dma16(uz0 + f * 1024, &slots[wave][0][f * 512]);
                #pragma unroll
                for (int f = 0; f < 4; ++f) dma16(uz2 + f * 1024, &slots[wave][1][f * 512]);
            } else {                                    // waves 2-7: next s0
                #pragma unroll
                for (int g = 0; g < 4; ++g)
                    dma16(gbase[g], &slots[wave][0][g * 512]);
            }
        }
        __syncthreads();   // B4: u2s ready; wz + next-s0 drained

        // ---- fused zz + z (waves 0,1): loc & raw tiles in-lane
        if (wave < 2) {
            floatx4 aL = (floatx4){zbL, zbL, zbL, zbL};
            floatx4 aR = (floatx4){zbR, zbR, zbR, zbR};
            #pragma unroll
            for (int ki = 0; ki < 4; ++ki) {
                bf16x8 a = *(const bf16x8*)&u2s[lrow][ki * 32 + quad * 8];
                bf16x8 bL = *(const bf16x8*)&slots[wave][0][ki * 512 + lane * 8];
                bf16x8 bR = *(const bf16x8*)&slots[wave][1][ki * 512 + lane * 8];
                aL = __builtin_amdgcn_mfma_f32_16x16x32_bf16(a, bL, aL, 0, 0, 0);
                aR = __builtin_amdgcn_mfma_f32_16x16x32_bf16(a, bR, aR, 0, 0, 0);
            }
            const int zc = (wave & 1) * 16 + lrow;
            #pragma unroll
            for (int r = 0; r < 4; ++r) {
                float raw = aR[r];
                float sp  = (raw > 20.0f) ? raw : log1pf(expf(raw));
                float zv  = aL[r] + sp * epsr[r];
                xh[nb][quad * 4 + r][8 + zc] = (__bf16)zv;
                out[((size_t)(n0 + quad * 4 + r) * T_LEN + t) * 32 + zc] = zv;
            }
            __builtin_amdgcn_sched_barrier(0);
            #pragma unroll
            for (int g = 0; g < 4; ++g) dma16(gbase[g],        &slots[wave][0][g * 512]);
            #pragma unroll
            for (int g = 0; g < 4; ++g) dma16(gbase[g] + 1024, &slots[wave][1][g * 512]);
        }
        a_cur = a_nxt;
        // z/a writes target buffer nb; next B1 orders them before gates reads.
    }
}

// ---------------- fallback: proven R4 VALU kernel (f32 hard-coded) --------
struct SM {
    float zx[4][40]; float h[4][256]; float u1[4][128]; float u2[4][128]; float zz[4][64];
};

__global__ __launch_bounds__(256) void seq_valu(
    const float* __restrict__ A, const float* __restrict__ eps,
    const float* __restrict__ z0, const float* __restrict__ h0, const float* __restrict__ c0,
    const float* __restrict__ Wih, const float* __restrict__ Whh,
    const float* __restrict__ bih, const float* __restrict__ bhh,
    const float* __restrict__ W1, const float* __restrict__ b1,
    const float* __restrict__ W2, const float* __restrict__ b2,
    const float* __restrict__ Wz, const float* __restrict__ bz, float* __restrict__ out)
{
    __shared__ SM sm;
    const int tid = threadIdx.x;
    const int n0  = blockIdx.x * 4;
    if (tid < 128) { int rr = tid >> 5, cc = tid & 31; sm.zx[rr][8 + cc] = z0[cc]; }
    for (int i = tid; i < 4 * 256; i += 256) sm.h[i >> 8][i & 255] = h0[i & 255];
    float c[4];
    #pragma unroll
    for (int rr = 0; rr < 4; ++rr) c[rr] = c0[tid];
    float gbias[4];
    #pragma unroll
    for (int g = 0; g < 4; ++g) gbias[g] = bih[g * 256 + tid] + bhh[g * 256 + tid];

    for (int t = 0; t < T_LEN; ++t) {
        if (tid < 32) { int rr = tid >> 3, cc = tid & 7;
            sm.zx[rr][cc] = A[((size_t)(n0 + rr) * T_LEN + t) * 8 + cc]; }
        __syncthreads();
        float acc[4][4];
        #pragma unroll
        for (int g = 0; g < 4; ++g)
            #pragma unroll
            for (int rr = 0; rr < 4; ++rr) acc[g][rr] = gbias[g];
        for (int k = 0; k < 40; ++k) {
            float xv[4];
            #pragma unroll
            for (int rr = 0; rr < 4; ++rr) xv[rr] = sm.zx[rr][k];
            #pragma unroll
            for (int g = 0; g < 4; ++g) {
                float w = Wih[(size_t)(g * 256 + tid) * 40 + k];
                #pragma unroll
                for (int rr = 0; rr < 4; ++rr) acc[g][rr] += w * xv[rr];
            }
        }
        for (int k = 0; k < 256; ++k) {
            float hv[4];
            #pragma unroll
            for (int rr = 0; rr < 4; ++rr) hv[rr] = sm.h[rr][k];
            #pragma unroll
            for (int g = 0; g < 4; ++g) {
                float w = Whh[(size_t)(g * 256 + tid) * 256 + k];
                #pragma unroll
                for (int rr = 0; rr < 4; ++rr) acc[g][rr] += w * hv[rr];
            }
        }
        __syncthreads();
        #pragma unroll
        for (int rr = 0; rr < 4; ++rr) {
            float iv = 1.0f / (1.0f + expf(-acc[0][rr]));
            float fv = 1.0f / (1.0f + expf(-acc[1][rr]));
            float gv = tanhf(acc[2][rr]);
            float ov = 1.0f / (1.0f + expf(-acc[3][rr]));
            float cn = fv * c[rr] + iv * gv;
            c[rr] = cn;
            sm.h[rr][tid] = ov * tanhf(cn);
        }
        __syncthreads();
        { int col = tid & 127, rb = (tid >> 7) * 2;
          float a0 = b1[col], a1 = a0;
          for (int k = 0; k < 256; ++k) { float w = W1[(size_t)col * 256 + k];
              a0 += w * sm.h[rb][k]; a1 += w * sm.h[rb + 1][k]; }
          sm.u1[rb][col] = fmaxf(a0, 0.0f); sm.u1[rb + 1][col] = fmaxf(a1, 0.0f); }
        __syncthreads();
        { int col = tid & 127, rb = (tid >> 7) * 2;
          float a0 = b2[col], a1 = a0;
          for (int k = 0; k < 128; ++k) { float w = W2[(size_t)col * 128 + k];
              a0 += w * sm.u1[rb][k]; a1 += w * sm.u1[rb + 1][k]; }
          sm.u2[rb][col] = fmaxf(a0, 0.0f); sm.u2[rb + 1][col] = fmaxf(a1, 0.0f); }
        __syncthreads();
        { int rr = tid >> 6, col = tid & 63;
          float a0 = bz[col];
          for (int k = 0; k < 128; ++k) a0 += Wz[(size_t)col * 128 + k] * sm.u2[rr][k];
          sm.zz[rr][col] = a0; }
        __syncthreads();
        if (tid < 128) {
            int rr = tid >> 5, cc = tid & 31;
            float loc = sm.zz[rr][cc], raw = sm.zz[rr][cc + 32];
            float sp  = (raw > 20.0f) ? raw : log1pf(expf(raw));
            float ev  = eps[((size_t)(n0 + rr) * T_LEN + t) * 32 + cc];
            float zv  = loc + sp * ev;
            sm.zx[rr][8 + cc] = zv;
            out[((size_t)(n0 + rr) * T_LEN + t) * 32 + cc] = zv;
        }
        __syncthreads();
    }
}

extern "C" void kernel_launch(void* const* d_in, const int* in_sizes, int n_in,
                              void* d_out, int out_size, void* d_ws, size_t ws_size,
                              hipStream_t stream)
{
    const float* A   = (const float*)d_in[0];
    const float* eps = (const float*)d_in[1];
    const float* z0  = (const float*)d_in[2];
    const float* h0  = (const float*)d_in[3];
    const float* c0  = (const float*)d_in[4];
    const float* Wih = (const float*)d_in[5];
    const float* Whh = (const float*)d_in[6];
    const float* bih = (const float*)d_in[7];
    const float* bhh = (const float*)d_in[8];
    const float* W1  = (const float*)d_in[9];
    const float* b1  = (const float*)d_in[10];
    const float* W2  = (const float*)d_in[11];
    const float* b2  = (const float*)d_in[12];
    const float* Wz  = (const float*)d_in[13];
    const float* bz  = (const float*)d_in[14];
    float* out = (float*)d_out;

    if (ws_size >= WS_NEEDED) {
        prep_kernel<<<188, 256, 0, stream>>>(Wih, Whh, W1, W2, Wz, (unsigned char*)d_ws);
        seq_mfma<<<64, 1024, 0, stream>>>(A, eps, z0, h0, c0,
                                          bih, bhh, b1, b2, bz,
                                          (const unsigned char*)d_ws, out);
    } else {
        seq_valu<<<256, 256, 0, stream>>>(A, eps, z0, h0, c0, Wih, Whh, bih, bhh,
                                          W1, b1, W2, b2, Wz, bz, out);
    }
}